// Round 6
// baseline (102.825 us; speedup 1.0000x reference)
//
#include <hip/hip_runtime.h>

#define EPS_F 1e-8f
#define EPT 4  // elements per thread; grid 1024 -> 4 blocks/CU, 4 chains/wave

typedef float vf4 __attribute__((ext_vector_type(4)));

__device__ __forceinline__ vf4 load4u(const float* p) {
    vf4 v;
    __builtin_memcpy(&v, p, 16);   // align-4 16B load -> global_load_dwordx4
    return v;
}

__device__ __forceinline__ float fast_rcp(float x) {
    return __builtin_amdgcn_rcpf(x);  // v_rcp_f32, ~1 ulp
}

__global__ void zero_out_kernel(float* out) { out[0] = 0.f; }

// Contribution of one directed edge (a->b) of a CCW polygon to
// 2*signed-Area(P ∩ [-W,W]x[-H,H]) via the boundary integral of
// h(y)=clamp(y,-H,H)+H over the edge clipped to the x-slab (vertical
// closure segments have dx=0 -> contribute 0). Split at y=±H crossings;
// trapezoid per piece is exact (h piecewise-linear). Branch-free, NaN-free.
__device__ __forceinline__ float edge_contrib(float ax, float ay,
                                              float bx, float by,
                                              float W, float H) {
    float dx = bx - ax, dy = by - ay;
    float sdx = (fabsf(dx) < 1e-20f) ? 1e-20f : dx;
    float sdy = (fabsf(dy) < 1e-20f) ? 1e-20f : dy;
    float rdx = fast_rcp(sdx);
    float rdy = fast_rcp(sdy);

    float tA = (-W - ax) * rdx;
    float tB = ( W - ax) * rdx;
    float ta = fmaxf(fminf(tA, tB), 0.f);
    float tb = fminf(fmaxf(tA, tB), 1.f);
    tb = fmaxf(ta, tb);

    float u0 = (-H - ay) * rdy;
    float u1 = ( H - ay) * rdy;
    float tm0 = fminf(u0, u1), tm1 = fmaxf(u0, u1);
    float t1 = fminf(fmaxf(tm0, ta), tb);
    float t2 = fminf(fmaxf(tm1, ta), tb);

    float x0 = fmaf(ta, dx, ax), y0 = fmaf(ta, dy, ay);
    float x1 = fmaf(t1, dx, ax), y1 = fmaf(t1, dy, ay);
    float x2 = fmaf(t2, dx, ax), y2 = fmaf(t2, dy, ay);
    float x3 = fmaf(tb, dx, ax), y3 = fmaf(tb, dy, ay);
    float h0 = fminf(fmaxf(y0, -H), H) + H;
    float h1 = fminf(fmaxf(y1, -H), H) + H;
    float h2 = fminf(fmaxf(y2, -H), H) + H;
    float h3 = fminf(fmaxf(y3, -H), H) + H;

    return (x1 - x0) * (h0 + h1) + (x2 - x1) * (h1 + h2) + (x3 - x2) * (h2 + h3);
}

__global__ __launch_bounds__(256, 4) void iou3d_loss_kernel(
    const float* __restrict__ pred, const float* __restrict__ target,
    const float* __restrict__ weight, float* __restrict__ out,
    int N, float invN)
{
    int base = blockIdx.x * (256 * EPT) + threadIdx.x;

    // ---- phase 1: hoist ALL loads as 16B vector loads (one vmcnt drain) ----
    // box layout [x,y,z,w,h,l,yaw]: A0 = floats 0..3, A1 = floats 3..6
    vf4 A0[EPT], A1[EPT], B0[EPT], B1[EPT];
    float wgt[EPT];
    #pragma unroll
    for (int e = 0; e < EPT; ++e) {
        int i = base + e * 256;
        int j = (i < N) ? i : 0;              // safe index; wgt=0 kills OOB
        long o = (long)j * 7;
        A0[e] = load4u(pred + o);
        A1[e] = load4u(pred + o + 3);
        B0[e] = load4u(target + o);
        B1[e] = load4u(target + o + 3);
        wgt[e] = (i < N) ? weight[j] : 0.f;
    }

    // ---- phase 2: EPT independent compute chains ----
    float val = 0.f;
    #pragma unroll
    for (int e = 0; e < EPT; ++e) {
        // b1: x=A0.x y=A0.y z=A0.z w=A1.x h=A1.y l=A1.z yaw=A1.w
        float s1, c1, s2, c2;
        __sincosf(A1[e].w, &s1, &c1);
        __sincosf(B1[e].w, &s2, &c2);
        float cd = c1 * c2 + s1 * s2;          // cos(a2-a1)
        float sd = c1 * s2 - s1 * c2;          // sin(a2-a1)
        float dxc = B0[e].x - A0[e].x, dyc = B0[e].y - A0[e].y;
        float tx =  c1 * dxc + s1 * dyc;
        float ty = -s1 * dxc + c1 * dyc;
        float W = 0.5f * A1[e].x, H = 0.5f * A1[e].y;
        float w2 = 0.5f * B1[e].x, h2 = 0.5f * B1[e].y;

        // box2 corners in box1 frame (CCW)
        float cw = cd * w2, sw = sd * w2, ch = cd * h2, sh = sd * h2;
        float q0x =  cw - sh + tx, q0y =  sw + ch + ty;
        float q1x = -cw - sh + tx, q1y = -sw + ch + ty;
        float q2x = -cw + sh + tx, q2y = -sw - ch + ty;
        float q3x =  cw + sh + tx, q3y =  sw - ch + ty;

        float s  = edge_contrib(q0x, q0y, q1x, q1y, W, H)
                 + edge_contrib(q1x, q1y, q2x, q2y, W, H)
                 + edge_contrib(q2x, q2y, q3x, q3y, W, H)
                 + edge_contrib(q3x, q3y, q0x, q0y, W, H);
        float area = 0.5f * fabsf(s);

        float zmax = fminf(A0[e].z + 0.5f * A1[e].z, B0[e].z + 0.5f * B1[e].z);
        float zmin = fmaxf(A0[e].z - 0.5f * A1[e].z, B0[e].z - 0.5f * B1[e].z);
        float inter3d = area * fmaxf(zmax - zmin, 0.f);
        float v1 = A1[e].x * A1[e].y * A1[e].z;
        float v2 = B1[e].x * B1[e].y * B1[e].z;
        float iou = inter3d * fast_rcp(v1 + v2 - inter3d + EPS_F);
        val += (1.f - iou) * wgt[e];
    }

    // ---- reduction: wave64 shuffle -> LDS -> one atomic per block ----
    #pragma unroll
    for (int off = 32; off > 0; off >>= 1) val += __shfl_down(val, off, 64);
    __shared__ float wsum[4];
    int lane = threadIdx.x & 63, wid = threadIdx.x >> 6;
    if (lane == 0) wsum[wid] = val;
    __syncthreads();
    if (threadIdx.x == 0) {
        float ssum = (wsum[0] + wsum[1] + wsum[2] + wsum[3]) * invN;
        atomicAdd(out, ssum);
    }
}

extern "C" void kernel_launch(void* const* d_in, const int* in_sizes, int n_in,
                              void* d_out, int out_size, void* d_ws, size_t ws_size,
                              hipStream_t stream) {
    const float* pred   = (const float*)d_in[0];
    const float* target = (const float*)d_in[1];
    const float* weight = (const float*)d_in[2];
    float* out = (float*)d_out;
    int N = in_sizes[2];  // weight element count

    zero_out_kernel<<<1, 1, 0, stream>>>(out);
    int block = 256;
    int grid = (N + block * EPT - 1) / (block * EPT);
    iou3d_loss_kernel<<<grid, block, 0, stream>>>(pred, target, weight, out,
                                                  N, 1.f / (float)N);
}